// Round 1
// baseline (71.711 us; speedup 1.0000x reference)
//
#include <hip/hip_runtime.h>

// AOLayer: out[b,n,a] = ang(b,n,a) * rad(b,n,a)
//   d   = pos[b,n,:] - centers[a,:]
//   r2  = |d|^2
//   rad = sum_p coeffs[a,p] * exp(-exps[a,p] * r2)
//   ang = prod_k (powers[a,k]==0 ? 1 : powers[a,k]==1 ? d_k : d_k^2)
// B=512, N=32, A=256, P=6. Output float32, 4M elems (16 MB).

#define BB 512
#define NN 32
#define AA 256
#define PP 6
#define BN_PER_BLOCK 16   // (b,n) pairs handled per block; grid = 16384/16 = 1024

__global__ __launch_bounds__(AA) void ao_kernel(
    const float* __restrict__ pos,      // (B*N, 3)
    const float* __restrict__ centers,  // (A, 3)
    const float* __restrict__ exps,     // (A, P)
    const float* __restrict__ coeffs,   // (A, P)
    const int*   __restrict__ powers,   // (A, 3)
    float*       __restrict__ out)      // (B*N, A)
{
    const int a   = threadIdx.x;              // 0..255, one thread per atom
    const int bn0 = blockIdx.x * BN_PER_BLOCK;

    // Per-atom data cached in registers for the whole block's bn loop.
    const float cx = centers[a * 3 + 0];
    const float cy = centers[a * 3 + 1];
    const float cz = centers[a * 3 + 2];

    float e[PP], c[PP];
#pragma unroll
    for (int p = 0; p < PP; ++p) {
        e[p] = exps[a * PP + p];
        c[p] = coeffs[a * PP + p];
    }

    const int pwx = powers[a * 3 + 0];
    const int pwy = powers[a * 3 + 1];
    const int pwz = powers[a * 3 + 2];

#pragma unroll
    for (int i = 0; i < BN_PER_BLOCK; ++i) {
        const int bn = bn0 + i;
        // bn is block-uniform -> these compile to scalar loads (broadcast).
        const float px = pos[bn * 3 + 0];
        const float py = pos[bn * 3 + 1];
        const float pz = pos[bn * 3 + 2];

        const float dx = px - cx;
        const float dy = py - cy;
        const float dz = pz - cz;
        const float r2 = dx * dx + dy * dy + dz * dz;

        float rad = 0.0f;
#pragma unroll
        for (int p = 0; p < PP; ++p) {
            rad += c[p] * __expf(-e[p] * r2);
        }

        const float fx = (pwx == 0) ? 1.0f : ((pwx == 1) ? dx : dx * dx);
        const float fy = (pwy == 0) ? 1.0f : ((pwy == 1) ? dy : dy * dy);
        const float fz = (pwz == 0) ? 1.0f : ((pwz == 1) ? dz : dz * dz);

        out[(size_t)bn * AA + a] = fx * fy * fz * rad;
    }
}

extern "C" void kernel_launch(void* const* d_in, const int* in_sizes, int n_in,
                              void* d_out, int out_size, void* d_ws, size_t ws_size,
                              hipStream_t stream) {
    const float* pos     = (const float*)d_in[0];  // (B,N,3)
    const float* centers = (const float*)d_in[1];  // (A,3)
    const float* exps    = (const float*)d_in[2];  // (A,P)
    const float* coeffs  = (const float*)d_in[3];  // (A,P)
    const int*   powers  = (const int*)d_in[4];    // (A,3)
    float* out = (float*)d_out;                    // (B,N,A)

    const int total_bn = BB * NN;                  // 16384
    const int grid = total_bn / BN_PER_BLOCK;      // 1024 blocks
    ao_kernel<<<grid, AA, 0, stream>>>(pos, centers, exps, coeffs, powers, out);
}

// Round 2
// 70.139 us; speedup vs baseline: 1.0224x; 1.0224x over previous
//
#include <hip/hip_runtime.h>

// AOLayer: out[b,n,a] = ang(b,n,a) * rad(b,n,a)
//   d   = pos[b,n,:] - centers[a,:]
//   r2  = |d|^2
//   rad = sum_p coeffs[a,p] * exp(-exps[a,p] * r2)
//       = sum_p coeffs[a,p] * exp2(ke[a,p] * r2),  ke = -exps*log2(e)  (hoisted)
//   ang = prod_k f_k(d_k),  f(d) = a0 + d*(a1 + d*a2) with one-hot a0/a1/a2
//         from powers[a,k] in {0,1,2}  (2 FMAs, no per-iter selects)
// B=512, N=32, A=256, P=6. Output float32, 4M elems (16 MB).

#define BB 512
#define NN 32
#define AA 256
#define PP 6
#define BNPB 8   // (b,n) pairs per block; grid = 16384/8 = 2048 blocks

#if defined(__has_builtin)
#  if __has_builtin(__builtin_amdgcn_exp2f)
#    define EXP2F(x) __builtin_amdgcn_exp2f(x)
#  else
#    define EXP2F(x) exp2f(x)
#  endif
#else
#  define EXP2F(x) exp2f(x)
#endif

__global__ __launch_bounds__(AA) void ao_kernel(
    const float* __restrict__ pos,      // (B*N, 3)
    const float* __restrict__ centers,  // (A, 3)
    const float* __restrict__ exps,     // (A, P)
    const float* __restrict__ coeffs,   // (A, P)
    const int*   __restrict__ powers,   // (A, 3)
    float*       __restrict__ out)      // (B*N, A)
{
    const int a   = threadIdx.x;              // 0..255, one thread per atom
    const int bn0 = blockIdx.x * BNPB;

    // Per-atom constants, cached in registers across the bn loop.
    const float cx = centers[a * 3 + 0];
    const float cy = centers[a * 3 + 1];
    const float cz = centers[a * 3 + 2];

    float ke[PP], c[PP];
#pragma unroll
    for (int p = 0; p < PP; ++p) {
        ke[p] = exps[a * PP + p] * (-1.4426950408889634f);  // -log2(e)*exp
        c[p]  = coeffs[a * PP + p];
    }

    const int pwx = powers[a * 3 + 0];
    const int pwy = powers[a * 3 + 1];
    const int pwz = powers[a * 3 + 2];
    // one-hot polynomial coeffs: f(d) = a0 + d*(a1 + d*a2)
    const float a0x = (pwx == 0) ? 1.0f : 0.0f;
    const float a1x = (pwx == 1) ? 1.0f : 0.0f;
    const float a2x = (pwx == 2) ? 1.0f : 0.0f;
    const float a0y = (pwy == 0) ? 1.0f : 0.0f;
    const float a1y = (pwy == 1) ? 1.0f : 0.0f;
    const float a2y = (pwy == 2) ? 1.0f : 0.0f;
    const float a0z = (pwz == 0) ? 1.0f : 0.0f;
    const float a1z = (pwz == 1) ? 1.0f : 0.0f;
    const float a2z = (pwz == 2) ? 1.0f : 0.0f;

#pragma unroll
    for (int i = 0; i < BNPB; ++i) {
        const int bn = bn0 + i;
        // bn is block-uniform -> scalar (broadcast) loads.
        const float px = pos[bn * 3 + 0];
        const float py = pos[bn * 3 + 1];
        const float pz = pos[bn * 3 + 2];

        const float dx = px - cx;
        const float dy = py - cy;
        const float dz = pz - cz;
        const float r2 = dx * dx + dy * dy + dz * dz;

        float rad = 0.0f;
#pragma unroll
        for (int p = 0; p < PP; ++p) {
            rad += c[p] * EXP2F(ke[p] * r2);   // 1 mul + v_exp_f32 + 1 fma
        }

        const float fx = a0x + dx * (a1x + dx * a2x);  // 2 fma
        const float fy = a0y + dy * (a1y + dy * a2y);
        const float fz = a0z + dz * (a1z + dz * a2z);

        out[(size_t)bn * AA + a] = fx * fy * fz * rad;
    }
}

extern "C" void kernel_launch(void* const* d_in, const int* in_sizes, int n_in,
                              void* d_out, int out_size, void* d_ws, size_t ws_size,
                              hipStream_t stream) {
    const float* pos     = (const float*)d_in[0];  // (B,N,3)
    const float* centers = (const float*)d_in[1];  // (A,3)
    const float* exps    = (const float*)d_in[2];  // (A,P)
    const float* coeffs  = (const float*)d_in[3];  // (A,P)
    const int*   powers  = (const int*)d_in[4];    // (A,3)
    float* out = (float*)d_out;                    // (B,N,A)

    const int total_bn = BB * NN;                  // 16384
    const int grid = total_bn / BNPB;              // 2048 blocks
    ao_kernel<<<grid, AA, 0, stream>>>(pos, centers, exps, coeffs, powers, out);
}